// Round 12
// baseline (266.237 us; speedup 1.0000x reference)
//
#include <hip/hip_runtime.h>

#define D 128
#define RPB 32          // rows per bucket
#define SHIFT 5         // log2(RPB)
#define PB 256          // partition blocks
#define CAP 1536        // max edges per bucket chunk (avg 512)
#define CAPP (CAP + RPB * 7)  // padded capacity (each row rounds up to x8)

typedef __attribute__((ext_vector_type(8))) short short8;
typedef __attribute__((ext_vector_type(4))) float f32x4;
typedef __attribute__((ext_vector_type(2))) float f32x2;
typedef __attribute__((ext_vector_type(4))) int int4v;

// ---- bf16 pack helpers (round-to-nearest-even)
__device__ inline unsigned bfr(float f) {
  unsigned u = __float_as_uint(f);
  return (u + 0x7fffu + ((u >> 16) & 1u)) >> 16;
}
__device__ inline unsigned pack2(float lo, float hi) {
  return bfr(lo) | (bfr(hi) << 16);
}

// ---------------- w: W1 fp32 -> bf16 transposed Wtg (64 blocks) + zero vpart2 (1 block)
__global__ __launch_bounds__(256) void k_w(const float* __restrict__ W,
                                           unsigned short* __restrict__ Wtg,
                                           float* __restrict__ vpart2) {
  int b = blockIdx.x, t = threadIdx.x;
  if (b < 64) {
    int i = b * 256 + t;
    int k = i >> 7, n = i & 127;
    Wtg[n * 128 + k] = (unsigned short)bfr(W[k * 128 + n]);
  } else {
    for (int i = t; i < 64 * D; i += 256) vpart2[i] = 0.f;
  }
}

// ---------------- FUSED: hist (PB blocks) || MFMA gemm (NG blocks).  (r8-exact)
__global__ __launch_bounds__(256) void k_hist_gemm(
    const int* __restrict__ dst, const int* __restrict__ src,
    int* __restrict__ phT, const float* __restrict__ x,
    const unsigned short* __restrict__ Wtg, unsigned short* __restrict__ hu8,
    int M, int E, int NBKT, int ECH, int K2) {
  __shared__ int shm[6400];  // 25.6 KB: hist or gemm x-tile
  int p = blockIdx.x, t = threadIdx.x;

  if (p < PB) {
    // ---- hist role: dual LDS histograms, nt int4 edge loads
    int b = p;
    int* histD = shm;
    int* histS = shm + NBKT;
    for (int k = t; k < K2; k += 256) shm[k] = 0;
    __syncthreads();
    int st = b * ECH, en = min(E, st + ECH);
    for (int i = st + t * 4; i < en; i += 1024) {
      if (i + 3 < en) {
        int4v d4 = __builtin_nontemporal_load((const int4v*)(dst + i));
        int4v s4 = __builtin_nontemporal_load((const int4v*)(src + i));
        atomicAdd(&histD[d4.x >> SHIFT], 1);
        atomicAdd(&histD[d4.y >> SHIFT], 1);
        atomicAdd(&histD[d4.z >> SHIFT], 1);
        atomicAdd(&histD[d4.w >> SHIFT], 1);
        atomicAdd(&histS[s4.x >> SHIFT], 1);
        atomicAdd(&histS[s4.y >> SHIFT], 1);
        atomicAdd(&histS[s4.z >> SHIFT], 1);
        atomicAdd(&histS[s4.w >> SHIFT], 1);
      } else {
        for (int j = i; j < en; ++j) {
          atomicAdd(&histD[dst[j] >> SHIFT], 1);
          atomicAdd(&histS[src[j] >> SHIFT], 1);
        }
      }
    }
    __syncthreads();
    for (int k = t; k < K2; k += 256) phT[(size_t)b * K2 + k] = shm[k];
    return;
  }

  // ---- MFMA gemm role: h = x@W1 (unscaled), fp8 e4m3 packed (r3-exact)
  int row0 = (p - PB) * 64;
  if (row0 >= M) return;
  unsigned short* xs = (unsigned short*)shm;  // [64][136]

  for (int i = t; i < 2048; i += 256) {
    int r = i >> 5;
    int rg = row0 + r;
    int rc = rg < M ? rg : M - 1;
    float4 v = ((const float4*)x)[(size_t)rc * 32 + (i & 31)];
    *(uint2*)&xs[r * 136 + (i & 31) * 4] = make_uint2(pack2(v.x, v.y), pack2(v.z, v.w));
  }
  __syncthreads();

  int lane = t & 63;
  int wid = t >> 6;
  int l15 = lane & 15;
  int quad = lane >> 4;
  int mloc = wid * 16 + l15;

  f32x4 acc[8];
  #pragma unroll
  for (int ct = 0; ct < 8; ++ct) acc[ct] = (f32x4){0.f, 0.f, 0.f, 0.f};

  #pragma unroll
  for (int k0 = 0; k0 < 128; k0 += 32) {
    short8 af = *(const short8*)&xs[mloc * 136 + k0 + quad * 8];
    #pragma unroll
    for (int ct = 0; ct < 8; ++ct) {
      short8 bf = *(const short8*)(Wtg + (ct * 16 + l15) * 128 + k0 + quad * 8);
      acc[ct] = __builtin_amdgcn_mfma_f32_16x16x32_bf16(af, bf, acc[ct], 0, 0, 0);
    }
  }

  int rowbase = row0 + wid * 16 + quad * 4;
  #pragma unroll
  for (int ct = 0; ct < 8; ++ct) {
    #pragma unroll
    for (int r = 0; r < 4; ++r) {
      float v = acc[ct][r];
      float vp = __shfl_xor(v, 1, 64);
      int row = rowbase + r;
      if (!(lane & 1) && row < M) {
        int pk = __builtin_amdgcn_cvt_pk_fp8_f32(v, vp, 0, false);
        hu8[(size_t)row * 64 + ct * 8 + (l15 >> 1)] = (unsigned short)(pk & 0xffff);
      }
    }
  }
}

// ---------------- tots: per-bucket totals; also persist per-64-block-group
// partials gpart[4][K2] so the scan3 rewrite can split the b-range 4 ways.
__global__ __launch_bounds__(256) void k_tots(const int* __restrict__ phT,
                                              int* __restrict__ tot,
                                              int* __restrict__ gpart, int K2) {
  __shared__ int part[4][64];
  int t = threadIdx.x;
  int c = t & 63, g = t >> 6;
  int k = blockIdx.x * 64 + c;
  int s = 0;
  if (k < K2) {
    for (int b = g * 64; b < g * 64 + 64; ++b)
      s += phT[(size_t)b * K2 + k];
    gpart[(size_t)g * K2 + k] = s;
  }
  part[g][c] = s;
  __syncthreads();
  if (g == 0 && k < K2)
    tot[k] = part[0][c] + part[1][c] + part[2][c] + part[3][c];
}

// ---------------- scan3: redundant in-LDS exclusive scan of tot, then rewrite
// of ONE (column-range, b-group) slice per block.  Grid = 4*TB.
__global__ __launch_bounds__(256) void k_scan3(int* __restrict__ phT,
                                               const int* __restrict__ tot,
                                               const int* __restrict__ gpart,
                                               int K2) {
  __shared__ int ltot[6400];
  __shared__ int sc[256];
  int t = threadIdx.x;
  int kb = blockIdx.x >> 2, g = blockIdx.x & 3;
  for (int i = t; i < K2; i += 256) ltot[i] = tot[i];
  __syncthreads();
  int C = (K2 + 255) / 256;
  int c0 = t * C;
  int s = 0;
  for (int j = 0; j < C; ++j) {
    int idx = c0 + j;
    if (idx < K2) s += ltot[idx];
  }
  sc[t] = s;
  __syncthreads();
  for (int off = 1; off < 256; off <<= 1) {
    int x = (t >= off) ? sc[t - off] : 0;
    __syncthreads();
    sc[t] += x;
    __syncthreads();
  }
  int run = sc[t] - s;  // exclusive base for this thread's chunk
  for (int j = 0; j < C; ++j) {
    int idx = c0 + j;
    if (idx < K2) {
      int v = ltot[idx];
      ltot[idx] = run;
      run += v;
    }
  }
  __syncthreads();

  int k = kb * 256 + t;
  if (k < K2) {
    int r = ltot[k];
    if (g > 0) r += gpart[k];
    if (g > 1) r += gpart[(size_t)K2 + k];
    if (g > 2) r += gpart[(size_t)2 * K2 + k];
    for (int b = g * 64; b < g * 64 + 64; ++b) {
      size_t idx = (size_t)b * K2 + k;
      int v = phT[idx];
      phT[idx] = r;
      r += v;
    }
  }
}

// ---------------- scat: SPLIT dual scatter, 1024 threads/block (r8-exact).
__global__ __launch_bounds__(1024) void k_scat(
    const int* __restrict__ src, const int* __restrict__ dst,
    const int* __restrict__ phT, int* __restrict__ eb,
    int E, int NBKT, int ECH, int K2) {
  __shared__ int cur[3200];
  int p = blockIdx.x, t = threadIdx.x;

  if (p < PB) {
    int b = ((p & 7) << 5) | (p >> 3);
    for (int k = t; k < NBKT; k += 1024) cur[k] = phT[(size_t)b * K2 + k];
    __syncthreads();
    int st = b * ECH, en = min(E, st + ECH);
    for (int i = st + t * 4; i < en; i += 4096) {
      if (i + 3 < en) {
        int4 s4 = *(const int4*)(src + i);
        int4 d4 = *(const int4*)(dst + i);
        int p0 = atomicAdd(&cur[d4.x >> SHIFT], 1);
        int p1 = atomicAdd(&cur[d4.y >> SHIFT], 1);
        int p2 = atomicAdd(&cur[d4.z >> SHIFT], 1);
        int p3 = atomicAdd(&cur[d4.w >> SHIFT], 1);
        eb[p0] = s4.x | ((d4.x & (RPB - 1)) << 26);
        eb[p1] = s4.y | ((d4.y & (RPB - 1)) << 26);
        eb[p2] = s4.z | ((d4.z & (RPB - 1)) << 26);
        eb[p3] = s4.w | ((d4.w & (RPB - 1)) << 26);
      } else {
        for (int j = i; j < en; ++j) {
          int d = dst[j], s = src[j];
          int pos = atomicAdd(&cur[d >> SHIFT], 1);
          eb[pos] = s | ((d & (RPB - 1)) << 26);
        }
      }
    }
  } else {
    int p2 = p - PB;
    int b = ((p2 & 7) << 5) | (p2 >> 3);
    for (int k = t; k < NBKT; k += 1024) cur[k] = phT[(size_t)b * K2 + NBKT + k];
    __syncthreads();
    int st = b * ECH, en = min(E, st + ECH);
    for (int i = st + t * 4; i < en; i += 4096) {
      if (i + 3 < en) {
        int4 s4 = *(const int4*)(src + i);
        int4 d4 = *(const int4*)(dst + i);
        int q0 = atomicAdd(&cur[s4.x >> SHIFT], 1);
        int q1 = atomicAdd(&cur[s4.y >> SHIFT], 1);
        int q2 = atomicAdd(&cur[s4.z >> SHIFT], 1);
        int q3 = atomicAdd(&cur[s4.w >> SHIFT], 1);
        eb[q0] = d4.x | ((s4.x & (RPB - 1)) << 26);
        eb[q1] = d4.y | ((s4.y & (RPB - 1)) << 26);
        eb[q2] = d4.z | ((s4.z & (RPB - 1)) << 26);
        eb[q3] = d4.w | ((s4.w & (RPB - 1)) << 26);
      } else {
        for (int j = i; j < en; ++j) {
          int d = dst[j], s = src[j];
          int qos = atomicAdd(&cur[s >> SHIFT], 1);
          eb[qos] = d | ((s & (RPB - 1)) << 26);
        }
      }
    }
  }
}

// ---------------- rowdeg: per-dst-bucket LDS count of local rows -> dinv
__global__ __launch_bounds__(256) void k_rowdeg(const int* __restrict__ eb,
                                                const int* __restrict__ phT,
                                                float* __restrict__ dinv,
                                                int N, int NBKT) {
  __shared__ int cnt[RPB];
  int bkt = blockIdx.x, t = threadIdx.x;
  if (t < RPB) cnt[t] = 0;
  __syncthreads();
  int lo = phT[bkt];
  int hi = phT[bkt + 1];
  for (int i = lo + t; i < hi; i += 256)
    atomicAdd(&cnt[(unsigned)eb[i] >> 26], 1);
  __syncthreads();
  if (t < RPB) {
    int r = bkt * RPB + t;
    if (r < N) dinv[r] = rsqrtf((float)cnt[t] + 1.0f);
  }
}

// ---------------- bucketed aggregate, HALF-WAVE EDGE PAIRING:
// one global_load_dword covers 2 edges (lanes 0-31 = edge j, lanes 32-63 =
// edge j+1, 4B/lane); 8-deep batch = 16 edges in flight at r8's register cost.
// 512 threads / 8 waves x 4 rows; halves combined via shfl_xor(32).
__global__ __launch_bounds__(512) void k_bagg(
    const unsigned short* __restrict__ hu8, const int* __restrict__ eb,
    const int* __restrict__ phT, const float* __restrict__ dinv,
    const float* __restrict__ b1, float* __restrict__ vpart2,
    int N, int E, int NBKT, int K2) {
  __shared__ int2 srtdi[CAPP];
  __shared__ int rcnt[RPB];
  __shared__ int rhp[RPB + 1];
  __shared__ int rcur[RPB];
  __shared__ float ssl[RPB];
  int bkt = blockIdx.x, t = threadIdx.x;
  int lane = t & 63, wid = t >> 6;
  int half = lane >> 5;          // 0: even edge of pair, 1: odd edge
  int lane4 = (lane & 31) << 2;  // byte offset of this lane's 4 columns
  const char* hub = (const char*)hu8;

  // ---- ssum prologue (src-table range of this bucket)
  if (t < RPB) ssl[t] = 0.f;
  __syncthreads();
  {
    int slo = phT[NBKT + bkt];
    int shi = (NBKT + bkt + 1 < K2) ? phT[NBKT + bkt + 1] : 2 * E;
    for (int i = slo + t; i < shi; i += 512) {
      int v = eb[i];
      atomicAdd(&ssl[(unsigned)v >> 26], dinv[v & 0x3FFFFFF]);
    }
  }

  int lo = phT[bkt];
  int hi = phT[bkt + 1];

  f32x4 acc[4];
  #pragma unroll
  for (int k = 0; k < 4; ++k) acc[k] = (f32x4){0.f, 0.f, 0.f, 0.f};

  for (int clo = lo; clo < hi; clo += CAP) {
    int cnt = min(CAP, hi - clo);
    __syncthreads();  // all waves done with srtdi/ssl of previous phase
    if (t < RPB) rcnt[t] = 0;
    __syncthreads();
    for (int i = t; i < cnt; i += 512) {
      int v = eb[clo + i];
      atomicAdd(&rcnt[(unsigned)v >> 26], 1);
    }
    __syncthreads();
    if (t < RPB) {
      int x = (rcnt[t] + 7) & ~7;  // padded count
      int orig = x;
      #pragma unroll
      for (int o = 1; o < RPB; o <<= 1) {
        int y = __shfl_up(x, o, 64);
        if (t >= o) x += y;
      }
      rhp[t + 1] = x;
      if (t == 0) rhp[0] = 0;
      rcur[t] = x - orig;  // padded start
    }
    __syncthreads();
    for (int i = t; i < cnt; i += 512) {
      int v = eb[clo + i];  // re-read, L2-hot
      int r = (unsigned)v >> 26;
      int pos = atomicAdd(&rcur[r], 1);
      int s = v & 0x3FFFFFF;
      srtdi[pos] = make_int2(s << 7, __float_as_int(dinv[s]));
    }
    __syncthreads();
    if (t < RPB) {  // fill pad region with weight-0 entries
      for (int i = rcur[t]; i < rhp[t + 1]; ++i) srtdi[i] = make_int2(0, 0);
    }
    __syncthreads();

    #pragma unroll
    for (int k = 0; k < 4; ++k) {
      int rl = wid + k * 8;
      int beg = rhp[rl], end = rhp[rl + 1];
      int j = beg;
      for (; j + 16 <= end; j += 16) {  // 16 edges = 8 pair-loads
        int2 e[8];
        #pragma unroll
        for (int p = 0; p < 8; ++p) e[p] = srtdi[j + 2 * p + half];
        unsigned v[8];
        #pragma unroll
        for (int p = 0; p < 8; ++p)
          v[p] = *(const unsigned*)(hub + (unsigned)e[p].x + lane4);
        #pragma unroll
        for (int p = 0; p < 8; ++p) {
          f32x2 f01 = __builtin_amdgcn_cvt_pk_f32_fp8((int)v[p], false);
          f32x2 f23 = __builtin_amdgcn_cvt_pk_f32_fp8((int)v[p], true);
          float w = __int_as_float(e[p].y);
          acc[k].x = fmaf(w, f01.x, acc[k].x);
          acc[k].y = fmaf(w, f01.y, acc[k].y);
          acc[k].z = fmaf(w, f23.x, acc[k].z);
          acc[k].w = fmaf(w, f23.y, acc[k].w);
        }
      }
      if (j < end) {  // exactly one 8-edge group remains (x8 padding)
        int2 e[4];
        #pragma unroll
        for (int p = 0; p < 4; ++p) e[p] = srtdi[j + 2 * p + half];
        unsigned v[4];
        #pragma unroll
        for (int p = 0; p < 4; ++p)
          v[p] = *(const unsigned*)(hub + (unsigned)e[p].x + lane4);
        #pragma unroll
        for (int p = 0; p < 4; ++p) {
          f32x2 f01 = __builtin_amdgcn_cvt_pk_f32_fp8((int)v[p], false);
          f32x2 f23 = __builtin_amdgcn_cvt_pk_f32_fp8((int)v[p], true);
          float w = __int_as_float(e[p].y);
          acc[k].x = fmaf(w, f01.x, acc[k].x);
          acc[k].y = fmaf(w, f01.y, acc[k].y);
          acc[k].z = fmaf(w, f23.x, acc[k].z);
          acc[k].w = fmaf(w, f23.y, acc[k].w);
        }
      }
    }
  }

  // combine the two edge-halves (lane L and L^32 hold same columns)
  #pragma unroll
  for (int k = 0; k < 4; ++k) {
    acc[k].x += __shfl_xor(acc[k].x, 32, 64);
    acc[k].y += __shfl_xor(acc[k].y, 32, 64);
    acc[k].z += __shfl_xor(acc[k].z, 32, 64);
    acc[k].w += __shfl_xor(acc[k].w, 32, 64);
  }

  // epilogue: a1 = relu(di*(acc + di*h_self) + b1); accumulate w*a1
  float4 bb = *(const float4*)(b1 + lane4);
  f32x4 v4 = (f32x4){0.f, 0.f, 0.f, 0.f};
  #pragma unroll
  for (int k = 0; k < 4; ++k) {
    int rl = wid + k * 8;
    int r = bkt * RPB + rl;
    if (r < N) {
      float di = dinv[r];
      unsigned gr = *(const unsigned*)(hub + ((unsigned)r << 7) + lane4);
      f32x2 g01 = __builtin_amdgcn_cvt_pk_f32_fp8((int)gr, false);
      f32x2 g23 = __builtin_amdgcn_cvt_pk_f32_fp8((int)gr, true);
      float w = di * (ssl[rl] + di);
      v4.x = fmaf(w, fmaxf(fmaf(di, fmaf(di, g01.x, acc[k].x), bb.x), 0.f), v4.x);
      v4.y = fmaf(w, fmaxf(fmaf(di, fmaf(di, g01.y, acc[k].y), bb.y), 0.f), v4.y);
      v4.z = fmaf(w, fmaxf(fmaf(di, fmaf(di, g23.x, acc[k].z), bb.z), 0.f), v4.z);
      v4.w = fmaf(w, fmaxf(fmaf(di, fmaf(di, g23.y, acc[k].w), bb.w), 0.f), v4.w);
    }
  }
  __syncthreads();  // done with srtdi -> reuse as reduction scratch
  f32x4* red = (f32x4*)srtdi;  // 8 waves x 32 lanes x 16B = 4KB
  if (half == 0) red[wid * 32 + (lane & 31)] = v4;
  __syncthreads();
  if (t < 32) {
    f32x4 s = (f32x4){0.f, 0.f, 0.f, 0.f};
    #pragma unroll
    for (int w = 0; w < 8; ++w) {
      f32x4 a = red[w * 32 + t];
      s.x += a.x; s.y += a.y; s.z += a.z; s.w += a.w;
    }
    float* vp = vpart2 + (size_t)(bkt & 63) * D + t * 4;
    atomicAdd(vp + 0, s.x);
    atomicAdd(vp + 1, s.y);
    atomicAdd(vp + 2, s.z);
    atomicAdd(vp + 3, s.w);
  }
}

// ---------------- final: v = sum partials; out = (1/N)*v@W2 + b2
__global__ __launch_bounds__(1024) void k_final(const float* __restrict__ vpart,
                                                int npart,
                                                const float* __restrict__ W2,
                                                const float* __restrict__ b2,
                                                float* __restrict__ out, float invN) {
  __shared__ float seg[8][128];
  __shared__ float vs[128];
  int t = threadIdx.x;
  int c = t & 127, sg = t >> 7;
  float s = 0.f;
  for (int b = sg; b < npart; b += 8) s += vpart[(size_t)b * D + c];
  seg[sg][c] = s;
  __syncthreads();
  if (t < 128) {
    float tot = 0.f;
    #pragma unroll
    for (int k = 0; k < 8; ++k) tot += seg[k][c];
    vs[c] = tot;
  }
  __syncthreads();
  if (t < 128) {
    float o = 0.f;
    for (int k = 0; k < 128; ++k) o = fmaf(vs[k], W2[k * D + c], o);
    out[c] = fmaf(o, invN, b2[c]);
  }
}

extern "C" void kernel_launch(void* const* d_in, const int* in_sizes, int n_in,
                              void* d_out, int out_size, void* d_ws, size_t ws_size,
                              hipStream_t stream) {
  const float* x  = (const float*)d_in[0];
  const int*   ei = (const int*)d_in[1];
  const float* W1 = (const float*)d_in[2];
  const float* b1 = (const float*)d_in[3];
  const float* W2 = (const float*)d_in[4];
  const float* b2 = (const float*)d_in[5];
  float* out = (float*)d_out;

  int N = in_sizes[0] / D;
  int E = in_sizes[1] / 2;
  const int* src = ei;
  const int* dst = ei + E;

  const int NBKT = (N + RPB - 1) / RPB;                    // 3125
  const int K2   = 2 * NBKT;                               // 6250 (both tables)
  const int ECH  = (((E + PB - 1) / PB) + 3) & ~3;         // 6252 (x4 aligned)
  const int TB   = (K2 + 255) / 256;                       // 25 (scan3 col-ranges)
  const int TBT  = (K2 + 63) / 64;                         // 98 (tots grid)
  const int NGEMM = (N + 63) / 64;                         // 1563

  char* p = (char*)d_ws;
  float* dinv  = (float*)p;      p += (size_t)N * 4;
  int*   tot   = (int*)p;        p += 8192 * 4;
  int*   gpart = (int*)p;        p += (size_t)4 * 8192 * 4;
  int*   phT   = (int*)p;        p += (size_t)PB * K2 * 4;
  int*   eb    = (int*)p;        p += (size_t)(2 * E) * 4;
  p = (char*)(((uintptr_t)p + 255) & ~(uintptr_t)255);
  unsigned short* Wtg = (unsigned short*)p;  p += 128 * 128 * 2;
  p = (char*)(((uintptr_t)p + 255) & ~(uintptr_t)255);
  unsigned short* hu8 = (unsigned short*)p;  p += (size_t)N * 64 * 2;
  p = (char*)(((uintptr_t)p + 255) & ~(uintptr_t)255);
  float* vpart2 = (float*)p;

  k_w<<<65, 256, 0, stream>>>(W1, Wtg, vpart2);

  k_hist_gemm<<<PB + NGEMM, 256, 0, stream>>>(dst, src, phT, x, Wtg, hu8,
                                              N, E, NBKT, ECH, K2);

  k_tots<<<TBT, 256, 0, stream>>>(phT, tot, gpart, K2);

  k_scan3<<<TB * 4, 256, 0, stream>>>(phT, tot, gpart, K2);

  k_scat<<<2 * PB, 1024, 0, stream>>>(src, dst, phT, eb, E, NBKT, ECH, K2);

  k_rowdeg<<<NBKT, 256, 0, stream>>>(eb, phT, dinv, N, NBKT);

  k_bagg<<<NBKT, 512, 0, stream>>>(hu8, eb, phT, dinv, b1, vpart2, N, E, NBKT, K2);

  k_final<<<1, 1024, 0, stream>>>(vpart2, 64, W2, b2, out, 1.0f / N);
}

// Round 13
// 246.133 us; speedup vs baseline: 1.0817x; 1.0817x over previous
//
#include <hip/hip_runtime.h>

#define D 128
#define RPB 32          // rows per bucket
#define SHIFT 5         // log2(RPB)
#define PB 256          // partition blocks
#define CAP 1536        // max edges per bucket chunk (avg 512)
#define CAPP (CAP + RPB * 7)  // padded capacity (each row rounds up to x8)

typedef __attribute__((ext_vector_type(8))) short short8;
typedef __attribute__((ext_vector_type(4))) float f32x4;
typedef __attribute__((ext_vector_type(2))) float f32x2;
typedef __attribute__((ext_vector_type(4))) int int4v;

// ---- bf16 pack helpers (round-to-nearest-even)
__device__ inline unsigned bfr(float f) {
  unsigned u = __float_as_uint(f);
  return (u + 0x7fffu + ((u >> 16) & 1u)) >> 16;
}
__device__ inline unsigned pack2(float lo, float hi) {
  return bfr(lo) | (bfr(hi) << 16);
}

// ---------------- w: W1 fp32 -> bf16 transposed Wtg (64 blocks) + zero vpart2 (1 block)
__global__ __launch_bounds__(256) void k_w(const float* __restrict__ W,
                                           unsigned short* __restrict__ Wtg,
                                           float* __restrict__ vpart2) {
  int b = blockIdx.x, t = threadIdx.x;
  if (b < 64) {
    int i = b * 256 + t;
    int k = i >> 7, n = i & 127;
    Wtg[n * 128 + k] = (unsigned short)bfr(W[k * 128 + n]);
  } else {
    for (int i = t; i < 64 * D; i += 256) vpart2[i] = 0.f;
  }
}

// ---------------- FUSED: hist (PB blocks) || MFMA gemm (NG blocks).  (r8-exact)
__global__ __launch_bounds__(256) void k_hist_gemm(
    const int* __restrict__ dst, const int* __restrict__ src,
    int* __restrict__ phT, const float* __restrict__ x,
    const unsigned short* __restrict__ Wtg, unsigned short* __restrict__ hu8,
    int M, int E, int NBKT, int ECH, int K2) {
  __shared__ int shm[6400];  // 25.6 KB: hist or gemm x-tile
  int p = blockIdx.x, t = threadIdx.x;

  if (p < PB) {
    // ---- hist role: dual LDS histograms, nt int4 edge loads
    int b = p;
    int* histD = shm;
    int* histS = shm + NBKT;
    for (int k = t; k < K2; k += 256) shm[k] = 0;
    __syncthreads();
    int st = b * ECH, en = min(E, st + ECH);
    for (int i = st + t * 4; i < en; i += 1024) {
      if (i + 3 < en) {
        int4v d4 = __builtin_nontemporal_load((const int4v*)(dst + i));
        int4v s4 = __builtin_nontemporal_load((const int4v*)(src + i));
        atomicAdd(&histD[d4.x >> SHIFT], 1);
        atomicAdd(&histD[d4.y >> SHIFT], 1);
        atomicAdd(&histD[d4.z >> SHIFT], 1);
        atomicAdd(&histD[d4.w >> SHIFT], 1);
        atomicAdd(&histS[s4.x >> SHIFT], 1);
        atomicAdd(&histS[s4.y >> SHIFT], 1);
        atomicAdd(&histS[s4.z >> SHIFT], 1);
        atomicAdd(&histS[s4.w >> SHIFT], 1);
      } else {
        for (int j = i; j < en; ++j) {
          atomicAdd(&histD[dst[j] >> SHIFT], 1);
          atomicAdd(&histS[src[j] >> SHIFT], 1);
        }
      }
    }
    __syncthreads();
    for (int k = t; k < K2; k += 256) phT[(size_t)b * K2 + k] = shm[k];
    return;
  }

  // ---- MFMA gemm role: h = x@W1 (unscaled), fp8 e4m3 packed (r3-exact)
  int row0 = (p - PB) * 64;
  if (row0 >= M) return;
  unsigned short* xs = (unsigned short*)shm;  // [64][136]

  for (int i = t; i < 2048; i += 256) {
    int r = i >> 5;
    int rg = row0 + r;
    int rc = rg < M ? rg : M - 1;
    float4 v = ((const float4*)x)[(size_t)rc * 32 + (i & 31)];
    *(uint2*)&xs[r * 136 + (i & 31) * 4] = make_uint2(pack2(v.x, v.y), pack2(v.z, v.w));
  }
  __syncthreads();

  int lane = t & 63;
  int wid = t >> 6;
  int l15 = lane & 15;
  int quad = lane >> 4;
  int mloc = wid * 16 + l15;

  f32x4 acc[8];
  #pragma unroll
  for (int ct = 0; ct < 8; ++ct) acc[ct] = (f32x4){0.f, 0.f, 0.f, 0.f};

  #pragma unroll
  for (int k0 = 0; k0 < 128; k0 += 32) {
    short8 af = *(const short8*)&xs[mloc * 136 + k0 + quad * 8];
    #pragma unroll
    for (int ct = 0; ct < 8; ++ct) {
      short8 bf = *(const short8*)(Wtg + (ct * 16 + l15) * 128 + k0 + quad * 8);
      acc[ct] = __builtin_amdgcn_mfma_f32_16x16x32_bf16(af, bf, acc[ct], 0, 0, 0);
    }
  }

  int rowbase = row0 + wid * 16 + quad * 4;
  #pragma unroll
  for (int ct = 0; ct < 8; ++ct) {
    #pragma unroll
    for (int r = 0; r < 4; ++r) {
      float v = acc[ct][r];
      float vp = __shfl_xor(v, 1, 64);
      int row = rowbase + r;
      if (!(lane & 1) && row < M) {
        int pk = __builtin_amdgcn_cvt_pk_fp8_f32(v, vp, 0, false);
        hu8[(size_t)row * 64 + ct * 8 + (l15 >> 1)] = (unsigned short)(pk & 0xffff);
      }
    }
  }
}

// ---------------- tots: per-bucket totals; also persist per-64-block-group
// partials gpart[4][K2] so the scan3 rewrite can split the b-range 4 ways.
__global__ __launch_bounds__(256) void k_tots(const int* __restrict__ phT,
                                              int* __restrict__ tot,
                                              int* __restrict__ gpart, int K2) {
  __shared__ int part[4][64];
  int t = threadIdx.x;
  int c = t & 63, g = t >> 6;
  int k = blockIdx.x * 64 + c;
  int s = 0;
  if (k < K2) {
    for (int b = g * 64; b < g * 64 + 64; ++b)
      s += phT[(size_t)b * K2 + k];
    gpart[(size_t)g * K2 + k] = s;
  }
  part[g][c] = s;
  __syncthreads();
  if (g == 0 && k < K2)
    tot[k] = part[0][c] + part[1][c] + part[2][c] + part[3][c];
}

// ---------------- scan3: redundant in-LDS exclusive scan of tot, then rewrite
// of ONE (column-range, b-group) slice per block.  Grid = 4*TB.
__global__ __launch_bounds__(256) void k_scan3(int* __restrict__ phT,
                                               const int* __restrict__ tot,
                                               const int* __restrict__ gpart,
                                               int K2) {
  __shared__ int ltot[6400];
  __shared__ int sc[256];
  int t = threadIdx.x;
  int kb = blockIdx.x >> 2, g = blockIdx.x & 3;
  for (int i = t; i < K2; i += 256) ltot[i] = tot[i];
  __syncthreads();
  int C = (K2 + 255) / 256;
  int c0 = t * C;
  int s = 0;
  for (int j = 0; j < C; ++j) {
    int idx = c0 + j;
    if (idx < K2) s += ltot[idx];
  }
  sc[t] = s;
  __syncthreads();
  for (int off = 1; off < 256; off <<= 1) {
    int x = (t >= off) ? sc[t - off] : 0;
    __syncthreads();
    sc[t] += x;
    __syncthreads();
  }
  int run = sc[t] - s;  // exclusive base for this thread's chunk
  for (int j = 0; j < C; ++j) {
    int idx = c0 + j;
    if (idx < K2) {
      int v = ltot[idx];
      ltot[idx] = run;
      run += v;
    }
  }
  __syncthreads();

  int k = kb * 256 + t;
  if (k < K2) {
    int r = ltot[k];
    if (g > 0) r += gpart[k];
    if (g > 1) r += gpart[(size_t)K2 + k];
    if (g > 2) r += gpart[(size_t)2 * K2 + k];
    for (int b = g * 64; b < g * 64 + 64; ++b) {
      size_t idx = (size_t)b * K2 + k;
      int v = phT[idx];
      phT[idx] = r;
      r += v;
    }
  }
}

// ---------------- scat: SPLIT dual scatter, 1024 threads/block (r8-exact).
__global__ __launch_bounds__(1024) void k_scat(
    const int* __restrict__ src, const int* __restrict__ dst,
    const int* __restrict__ phT, int* __restrict__ eb,
    int E, int NBKT, int ECH, int K2) {
  __shared__ int cur[3200];
  int p = blockIdx.x, t = threadIdx.x;

  if (p < PB) {
    int b = ((p & 7) << 5) | (p >> 3);
    for (int k = t; k < NBKT; k += 1024) cur[k] = phT[(size_t)b * K2 + k];
    __syncthreads();
    int st = b * ECH, en = min(E, st + ECH);
    for (int i = st + t * 4; i < en; i += 4096) {
      if (i + 3 < en) {
        int4 s4 = *(const int4*)(src + i);
        int4 d4 = *(const int4*)(dst + i);
        int p0 = atomicAdd(&cur[d4.x >> SHIFT], 1);
        int p1 = atomicAdd(&cur[d4.y >> SHIFT], 1);
        int p2 = atomicAdd(&cur[d4.z >> SHIFT], 1);
        int p3 = atomicAdd(&cur[d4.w >> SHIFT], 1);
        eb[p0] = s4.x | ((d4.x & (RPB - 1)) << 26);
        eb[p1] = s4.y | ((d4.y & (RPB - 1)) << 26);
        eb[p2] = s4.z | ((d4.z & (RPB - 1)) << 26);
        eb[p3] = s4.w | ((d4.w & (RPB - 1)) << 26);
      } else {
        for (int j = i; j < en; ++j) {
          int d = dst[j], s = src[j];
          int pos = atomicAdd(&cur[d >> SHIFT], 1);
          eb[pos] = s | ((d & (RPB - 1)) << 26);
        }
      }
    }
  } else {
    int p2 = p - PB;
    int b = ((p2 & 7) << 5) | (p2 >> 3);
    for (int k = t; k < NBKT; k += 1024) cur[k] = phT[(size_t)b * K2 + NBKT + k];
    __syncthreads();
    int st = b * ECH, en = min(E, st + ECH);
    for (int i = st + t * 4; i < en; i += 4096) {
      if (i + 3 < en) {
        int4 s4 = *(const int4*)(src + i);
        int4 d4 = *(const int4*)(dst + i);
        int q0 = atomicAdd(&cur[s4.x >> SHIFT], 1);
        int q1 = atomicAdd(&cur[s4.y >> SHIFT], 1);
        int q2 = atomicAdd(&cur[s4.z >> SHIFT], 1);
        int q3 = atomicAdd(&cur[s4.w >> SHIFT], 1);
        eb[q0] = d4.x | ((s4.x & (RPB - 1)) << 26);
        eb[q1] = d4.y | ((s4.y & (RPB - 1)) << 26);
        eb[q2] = d4.z | ((s4.z & (RPB - 1)) << 26);
        eb[q3] = d4.w | ((s4.w & (RPB - 1)) << 26);
      } else {
        for (int j = i; j < en; ++j) {
          int d = dst[j], s = src[j];
          int qos = atomicAdd(&cur[s >> SHIFT], 1);
          eb[qos] = d | ((s & (RPB - 1)) << 26);
        }
      }
    }
  }
}

// ---------------- rowdeg: per-dst-bucket LDS count of local rows -> dinv
__global__ __launch_bounds__(256) void k_rowdeg(const int* __restrict__ eb,
                                                const int* __restrict__ phT,
                                                float* __restrict__ dinv,
                                                int N, int NBKT) {
  __shared__ int cnt[RPB];
  int bkt = blockIdx.x, t = threadIdx.x;
  if (t < RPB) cnt[t] = 0;
  __syncthreads();
  int lo = phT[bkt];
  int hi = phT[bkt + 1];
  for (int i = lo + t; i < hi; i += 256)
    atomicAdd(&cnt[(unsigned)eb[i] >> 26], 1);
  __syncthreads();
  if (t < RPB) {
    int r = bkt * RPB + t;
    if (r < N) dinv[r] = rsqrtf((float)cnt[t] + 1.0f);
  }
}

// ---------------- bucketed aggregate + fused ssum prologue + fused weighted reduce
// CHAMPION form (r11, 248.0us): 256thr, 36 VGPR, 8-deep batches, no raw[] LDS
// staging (eb re-read L2-hot), srtdi int2, epilogue atomicAdd into vpart2.
// r10 (16-deep: VGPR 48, -8us), r12 (pair-loads 512thr: VGPR 48, -19us) both
// regressed via occupancy; this is the measured local optimum.
__global__ __launch_bounds__(256) void k_bagg(
    const unsigned short* __restrict__ hu8, const int* __restrict__ eb,
    const int* __restrict__ phT, const float* __restrict__ dinv,
    const float* __restrict__ b1, float* __restrict__ vpart2,
    int N, int E, int NBKT, int K2) {
  __shared__ int2 srtdi[CAPP];
  __shared__ int rcnt[RPB];
  __shared__ int rhp[RPB + 1];
  __shared__ int rcur[RPB];
  __shared__ float ssl[RPB];
  int bkt = blockIdx.x, t = threadIdx.x;
  int lane = t & 63, wid = t >> 6;
  int lane2 = lane << 1;
  const char* hub = (const char*)hu8;

  // ---- ssum prologue (src-table range of this bucket)
  if (t < RPB) ssl[t] = 0.f;
  __syncthreads();
  {
    int slo = phT[NBKT + bkt];
    int shi = (NBKT + bkt + 1 < K2) ? phT[NBKT + bkt + 1] : 2 * E;
    for (int i = slo + t; i < shi; i += 256) {
      int v = eb[i];
      atomicAdd(&ssl[(unsigned)v >> 26], dinv[v & 0x3FFFFFF]);
    }
  }

  int lo = phT[bkt];
  int hi = phT[bkt + 1];

  f32x2 acc[8];
  #pragma unroll
  for (int k = 0; k < 8; ++k) acc[k] = (f32x2){0.f, 0.f};

  for (int clo = lo; clo < hi; clo += CAP) {
    int cnt = min(CAP, hi - clo);
    __syncthreads();  // all waves done with srtdi/ssl of previous phase
    if (t < RPB) rcnt[t] = 0;
    __syncthreads();
    for (int i = t; i < cnt; i += 256) {
      int v = eb[clo + i];
      atomicAdd(&rcnt[(unsigned)v >> 26], 1);
    }
    __syncthreads();
    if (t < RPB) {
      int x = (rcnt[t] + 7) & ~7;  // padded count
      int orig = x;
      #pragma unroll
      for (int o = 1; o < RPB; o <<= 1) {
        int y = __shfl_up(x, o, 64);
        if (t >= o) x += y;
      }
      rhp[t + 1] = x;
      if (t == 0) rhp[0] = 0;
      rcur[t] = x - orig;  // padded start
    }
    __syncthreads();
    for (int i = t; i < cnt; i += 256) {
      int v = eb[clo + i];  // re-read, L2-hot (just read in count pass)
      int r = (unsigned)v >> 26;
      int pos = atomicAdd(&rcur[r], 1);
      int s = v & 0x3FFFFFF;
      srtdi[pos] = make_int2(s << 7, __float_as_int(dinv[s]));
    }
    __syncthreads();
    if (t < RPB) {  // fill pad region with weight-0 entries
      for (int i = rcur[t]; i < rhp[t + 1]; ++i) srtdi[i] = make_int2(0, 0);
    }
    __syncthreads();

    #pragma unroll
    for (int k = 0; k < 8; ++k) {
      int rl = wid + k * 4;
      int beg = rhp[rl], end = rhp[rl + 1];
      for (int j = beg; j < end; j += 8) {
        #pragma unroll
        for (int d = 0; d < 8; ++d) {
          int2 e = srtdi[j + d];
          unsigned v = *(const unsigned short*)(hub + (unsigned)e.x + lane2);
          f32x2 f = __builtin_amdgcn_cvt_pk_f32_fp8((int)v, false);
          float w = __int_as_float(e.y);
          acc[k].x = fmaf(w, f.x, acc[k].x);
          acc[k].y = fmaf(w, f.y, acc[k].y);
        }
      }
    }
  }
  __syncthreads();

  // epilogue: a1 = relu(di*(acc + di*h_self) + b1); accumulate w*a1
  float2 bb = *(const float2*)(b1 + lane2);
  float vx = 0.f, vy = 0.f;
  #pragma unroll
  for (int k = 0; k < 8; ++k) {
    int rl = wid + k * 4;
    int r = bkt * RPB + rl;
    if (r < N) {
      float di = dinv[r];
      unsigned gr = *(const unsigned short*)(hub + ((unsigned)r << 7) + lane2);
      f32x2 fg = __builtin_amdgcn_cvt_pk_f32_fp8((int)gr, false);
      float hx = fmaxf(fmaf(di, fmaf(di, fg.x, acc[k].x), bb.x), 0.f);
      float hy = fmaxf(fmaf(di, fmaf(di, fg.y, acc[k].y), bb.y), 0.f);
      float w = di * (ssl[rl] + di);
      vx = fmaf(w, hx, vx);
      vy = fmaf(w, hy, vy);
    }
  }
  float2* red = (float2*)srtdi;  // reuse LDS (all srtdi reads done)
  red[t] = make_float2(vx, vy);
  __syncthreads();
  if (t < 64) {
    float2 a = red[t], b = red[t + 64], c = red[t + 128], d2 = red[t + 192];
    float* vp = vpart2 + (size_t)(bkt & 63) * D;
    atomicAdd(vp + t * 2,     (a.x + b.x) + (c.x + d2.x));
    atomicAdd(vp + t * 2 + 1, (a.y + b.y) + (c.y + d2.y));
  }
}

// ---------------- final: v = sum partials; out = (1/N)*v@W2 + b2
__global__ __launch_bounds__(1024) void k_final(const float* __restrict__ vpart,
                                                int npart,
                                                const float* __restrict__ W2,
                                                const float* __restrict__ b2,
                                                float* __restrict__ out, float invN) {
  __shared__ float seg[8][128];
  __shared__ float vs[128];
  int t = threadIdx.x;
  int c = t & 127, sg = t >> 7;
  float s = 0.f;
  for (int b = sg; b < npart; b += 8) s += vpart[(size_t)b * D + c];
  seg[sg][c] = s;
  __syncthreads();
  if (t < 128) {
    float tot = 0.f;
    #pragma unroll
    for (int k = 0; k < 8; ++k) tot += seg[k][c];
    vs[c] = tot;
  }
  __syncthreads();
  if (t < 128) {
    float o = 0.f;
    for (int k = 0; k < 128; ++k) o = fmaf(vs[k], W2[k * D + c], o);
    out[c] = fmaf(o, invN, b2[c]);
  }
}

extern "C" void kernel_launch(void* const* d_in, const int* in_sizes, int n_in,
                              void* d_out, int out_size, void* d_ws, size_t ws_size,
                              hipStream_t stream) {
  const float* x  = (const float*)d_in[0];
  const int*   ei = (const int*)d_in[1];
  const float* W1 = (const float*)d_in[2];
  const float* b1 = (const float*)d_in[3];
  const float* W2 = (const float*)d_in[4];
  const float* b2 = (const float*)d_in[5];
  float* out = (float*)d_out;

  int N = in_sizes[0] / D;
  int E = in_sizes[1] / 2;
  const int* src = ei;
  const int* dst = ei + E;

  const int NBKT = (N + RPB - 1) / RPB;                    // 3125
  const int K2   = 2 * NBKT;                               // 6250 (both tables)
  const int ECH  = (((E + PB - 1) / PB) + 3) & ~3;         // 6252 (x4 aligned)
  const int TB   = (K2 + 255) / 256;                       // 25 (scan3 col-ranges)
  const int TBT  = (K2 + 63) / 64;                         // 98 (tots grid)
  const int NGEMM = (N + 63) / 64;                         // 1563

  char* p = (char*)d_ws;
  float* dinv  = (float*)p;      p += (size_t)N * 4;
  int*   tot   = (int*)p;        p += 8192 * 4;
  int*   gpart = (int*)p;        p += (size_t)4 * 8192 * 4;
  int*   phT   = (int*)p;        p += (size_t)PB * K2 * 4;
  int*   eb    = (int*)p;        p += (size_t)(2 * E) * 4;
  p = (char*)(((uintptr_t)p + 255) & ~(uintptr_t)255);
  unsigned short* Wtg = (unsigned short*)p;  p += 128 * 128 * 2;
  p = (char*)(((uintptr_t)p + 255) & ~(uintptr_t)255);
  unsigned short* hu8 = (unsigned short*)p;  p += (size_t)N * 64 * 2;
  p = (char*)(((uintptr_t)p + 255) & ~(uintptr_t)255);
  float* vpart2 = (float*)p;

  k_w<<<65, 256, 0, stream>>>(W1, Wtg, vpart2);

  k_hist_gemm<<<PB + NGEMM, 256, 0, stream>>>(dst, src, phT, x, Wtg, hu8,
                                              N, E, NBKT, ECH, K2);

  k_tots<<<TBT, 256, 0, stream>>>(phT, tot, gpart, K2);

  k_scan3<<<TB * 4, 256, 0, stream>>>(phT, tot, gpart, K2);

  k_scat<<<2 * PB, 1024, 0, stream>>>(src, dst, phT, eb, E, NBKT, ECH, K2);

  k_rowdeg<<<NBKT, 256, 0, stream>>>(eb, phT, dinv, N, NBKT);

  k_bagg<<<NBKT, 256, 0, stream>>>(hu8, eb, phT, dinv, b1, vpart2, N, E, NBKT, K2);

  k_final<<<1, 1024, 0, stream>>>(vpart2, 64, W2, b2, out, 1.0f / N);
}